// Round 10
// baseline (598.757 us; speedup 1.0000x reference)
//
#include <hip/hip_runtime.h>
#include <math.h>

#define MM    2048
#define CC    64
#define RH    4
#define NIF   461
#define INS   512
#define EPSN  1e-6f

// diagnostic repeat factors (idempotent phases)
#define REP_K1 16
#define REP_K2 2
#define REP_K3 16
#define REP_K4 3

typedef unsigned long long u64;

// ---- workspace layout (float offsets) ----
#define OFF_P     ((size_t)0)          // 256 x 512 params
#define OFF_U2    ((size_t)131072)     // 256 x 2048
#define OFF_MRW   ((size_t)655360)     // 256 x 2048
#define OFF_SC    ((size_t)1179648)    // 256 x 2048 raw write scores
#define OFF_ALLOC ((size_t)1703936)    // 256 x 2048 allocation weights
#define OFF_WW    ((size_t)2228224)    // 256 x 2048 write weighting
#define OFF_PART  ((size_t)2752512)    // 256 x 8 x 4 x 64 pass-B acc partials
#define OFF_PSTAT ((size_t)3276800)    // 256 x 8 x 4 x 2 {m,s}

// ================= K1: interface + gates + u2 + mean-read =================
__global__ __launch_bounds__(512) void k1_interface(
    const float* __restrict__ xi, const float* __restrict__ W,
    const float* __restrict__ gamma, const float* __restrict__ beta,
    const float* __restrict__ read_w, const float* __restrict__ write_w,
    const float* __restrict__ usage, float* __restrict__ ws)
{
  const int b = blockIdx.x, tid = threadIdx.x;
  const int lane = tid & 63, wid = tid >> 6;
  __shared__ __align__(16) float s_xi[512], s_itf[512], s_act[512];
  __shared__ float sRed[24];

  #pragma unroll 1
  for (int rep = 0; rep < REP_K1; ++rep) {
  __syncthreads();
  s_xi[tid] = xi[(size_t)b*INS + tid];
  __syncthreads();

  {
    const float4 x0 = ((const float4*)s_xi)[lane*2];
    const float4 x1 = ((const float4*)s_xi)[lane*2+1];
    for (int col = wid; col < NIF; col += 8) {
      const float4* Wr = (const float4*)(W + (size_t)col*INS);
      float4 a0 = Wr[lane*2], a1 = Wr[lane*2+1];
      float p = a0.x*x0.x + a0.y*x0.y + a0.z*x0.z + a0.w*x0.w
              + a1.x*x1.x + a1.y*x1.y + a1.z*x1.z + a1.w*x1.w;
      #pragma unroll
      for (int off=1; off<64; off<<=1) p += __shfl_xor(p, off);
      if (lane==0) s_itf[col] = p;
    }
  }
  __syncthreads();

  {
    float v = (tid < NIF) ? s_itf[tid] : 0.f;
    float s = v, q = v*v;
    #pragma unroll
    for (int off=1; off<64; off<<=1) { s += __shfl_xor(s,off); q += __shfl_xor(q,off); }
    if (lane==0){ sRed[wid] = s; sRed[8+wid] = q; }
    __syncthreads();
    if (tid==0){
      float ts=0.f, tq=0.f;
      for (int i=0;i<8;i++){ ts+=sRed[i]; tq+=sRed[8+i]; }
      float mean = ts/(float)NIF;
      float var  = tq/(float)NIF - mean*mean;
      sRed[16]=mean; sRed[17]=rsqrtf(var+1e-5f);
    }
    __syncthreads();
    float mean = sRed[16], rstd = sRed[17];
    if (tid < NIF) {
      float g = (s_itf[tid]-mean)*rstd*gamma[tid] + beta[tid];
      float a;
      if      (tid < 256) a = tanhf(g);
      else if (tid < 260) a = fmaxf(g,0.f) + log1pf(expf(-fabsf(g)));
      else if (tid < 324) a = tanhf(g);
      else if (tid ==324) a = fmaxf(g,0.f) + log1pf(expf(-fabsf(g)));
      else if (tid < 389) a = 1.f/(1.f+expf(-g));
      else if (tid < 453) a = tanhf(g);
      else if (tid < 457) a = 1.f/(1.f+expf(-g));
      else if (tid < 460) a = g;
      else                a = 1.f/(1.f+expf(-g));
      s_act[tid] = a;
    }
  }
  __syncthreads();

  float* P = ws + OFF_P + (size_t)b*512;
  if (wid < 4) {
    float t = s_act[wid*64 + lane];
    float q = t*t;
    #pragma unroll
    for (int off=1; off<64; off<<=1) q += __shfl_xor(q,off);
    P[wid*64+lane] = t * (s_act[256+wid] / (sqrtf(q) + EPSN));
  } else if (wid == 4) {
    float t = s_act[260+lane];
    float q = t*t;
    #pragma unroll
    for (int off=1; off<64; off<<=1) q += __shfl_xor(q,off);
    P[256+lane] = t * (s_act[324] / (sqrtf(q) + EPSN));
  } else if (wid == 5) {
    P[320+lane] = s_act[325+lane];
    P[384+lane] = s_act[389+lane];
  } else if (wid == 6 && lane == 0) {
    float a0=s_act[457], a1=s_act[458], a2=s_act[459];
    float mx = fmaxf(a0, fmaxf(a1,a2));
    float e0=expf(a0-mx), e1=expf(a1-mx), e2=expf(a2-mx);
    float is = 1.f/(e0+e1+e2);
    P[448]=e0*is; P[449]=e1*is; P[450]=e2*is; P[451]=s_act[460];
  }

  {
    const float4* us4 = (const float4*)(usage   + (size_t)b*MM);
    const float4* wr4 = (const float4*)(write_w + (size_t)b*MM);
    const float4* rw4 = (const float4*)(read_w  + (size_t)b*RH*MM);
    const float fg0=s_act[453], fg1=s_act[454], fg2=s_act[455], fg3=s_act[456];
    float4 u = us4[tid], w = wr4[tid];
    float4 r0 = rw4[tid], r1 = rw4[512+tid], r2 = rw4[1024+tid], r3 = rw4[1536+tid];
    float4 mr, u2o;
    mr.x = 0.25f*(r0.x+r1.x+r2.x+r3.x);
    mr.y = 0.25f*(r0.y+r1.y+r2.y+r3.y);
    mr.z = 0.25f*(r0.z+r1.z+r2.z+r3.z);
    mr.w = 0.25f*(r0.w+r1.w+r2.w+r3.w);
    #define U2C(comp)                                                           \
    { float uu  = u.comp + (1.f-u.comp)*w.comp;                                 \
      float psi = (1.f-fg0*r0.comp)*(1.f-fg1*r1.comp)*(1.f-fg2*r2.comp)*(1.f-fg3*r3.comp); \
      u2o.comp = 1e-6f + (1.f-1e-6f)*(uu*psi); }
    U2C(x) U2C(y) U2C(z) U2C(w)
    #undef U2C
    ((float4*)(ws + OFF_MRW + (size_t)b*MM))[tid] = mr;
    ((float4*)(ws + OFF_U2  + (size_t)b*MM))[tid] = u2o;
  }
  } // rep
}

// ====== K2: heterogeneous — blocks [0,256): sort+alloc; [256,2304): scores ======
__global__ __launch_bounds__(256) void k2_fused(
    const float* __restrict__ memory, float* __restrict__ ws)
{
  __shared__ __align__(16) u64 sKeys[2048];
  __shared__ float sT[260];
  const int tid = threadIdx.x;

  #pragma unroll 1
  for (int rep = 0; rep < REP_K2; ++rep) {
  __syncthreads();
  if (blockIdx.x < 256) {
    // ---------------- sort + allocation path ----------------
    const int b = blockIdx.x;
    const int lane = tid & 63, w = tid >> 6;
    const float* u2p = ws + OFF_U2 + (size_t)b*MM;
    for (int i = tid; i < MM; i += 256)
      sKeys[i] = ((u64)__float_as_uint(u2p[i])<<32) | (unsigned)i;
    __syncthreads();

    for (int k = 2; k <= MM; k <<= 1) {
      for (int j = k >> 1; j > 0; j >>= 1) {
        #pragma unroll 4
        for (int c = tid; c < MM/2; c += 256) {
          int i   = ((c & ~(j-1)) << 1) | (c & (j-1));
          int ixj = i | j;
          u64 a = sKeys[i], d = sKeys[ixj];
          bool up = ((i & k) == 0);
          if ((a > d) == up) { sKeys[i] = d; sKeys[ixj] = a; }
        }
        __syncthreads();
      }
    }

    float p[8];
    {
      float run = 1.f;
      #pragma unroll
      for (int e = 0; e < 8; ++e) {
        float su = __uint_as_float((unsigned)(sKeys[tid*8+e]>>32));
        run *= su; p[e] = run;
      }
      sT[tid] = run;
    }
    __syncthreads();
    float v = sT[tid];
    float incl = v;
    #pragma unroll
    for (int off=1; off<64; off<<=1) {
      float n = __shfl_up(incl, off);
      if (lane >= off) incl *= n;
    }
    float excl = __shfl_up(incl, 1);
    if (lane == 0) excl = 1.f;
    if (lane == 63) sT[256 + w] = incl;
    __syncthreads();
    float base = 1.f;
    for (int ww2 = 0; ww2 < w; ++ww2) base *= sT[256 + ww2];
    float E = base * excl;

    float* allocp = ws + OFF_ALLOC + (size_t)b*MM;
    #pragma unroll
    for (int e = 0; e < 8; ++e) {
      u64 kk = sKeys[tid*8+e];
      float su = __uint_as_float((unsigned)(kk>>32));
      unsigned idx = (unsigned)(kk & 0xFFFFFFFFu);
      float cp = E * (e ? p[e-1] : 1.f);
      allocp[idx] = (1.f - su) * cp;
    }
  } else {
    // ---------------- write-key cosine score path ----------------
    const int f = blockIdx.x - 256;
    const int b = f >> 3, slice = f & 7;
    const int l16 = tid & 15, rowg = tid >> 4;
    const float* P = ws + OFF_P + (size_t)b*512;
    const float4 wk4 = ((const float4*)(P+256))[l16];
    const float4* mem4 = (const float4*)(memory + (size_t)b*MM*CC) + (size_t)slice*256*16;
    float* sc = ws + OFF_SC + (size_t)b*MM + slice*256;
    #pragma unroll 4
    for (int it = 0; it < 16; ++it) {
      int m = it*16 + rowg;
      float4 vv = mem4[m*16 + l16];
      float d = vv.x*wk4.x + vv.y*wk4.y + vv.z*wk4.z + vv.w*wk4.w;
      float q = vv.x*vv.x + vv.y*vv.y + vv.z*vv.z + vv.w*vv.w;
      #pragma unroll
      for (int off=1; off<16; off<<=1){ d += __shfl_xor(d,off); q += __shfl_xor(q,off); }
      if (l16==0) sc[m] = d / (sqrtf(q)+EPSN);
    }
  }
  } // rep
}

// ============ K3: softmax over write scores + write weighting =============
__global__ __launch_bounds__(256) void k3_ww(float* __restrict__ ws)
{
  const int b = blockIdx.x, tid = threadIdx.x;
  const int lane = tid & 63, w = tid >> 6;
  __shared__ float sR[8];

  #pragma unroll 1
  for (int rep = 0; rep < REP_K3; ++rep) {
  __syncthreads();
  const float4* sc4 = (const float4*)(ws + OFF_SC + (size_t)b*MM);
  float4 v0 = sc4[tid*2], v1 = sc4[tid*2+1];
  float m = fmaxf(fmaxf(fmaxf(v0.x,v0.y),fmaxf(v0.z,v0.w)),
                  fmaxf(fmaxf(v1.x,v1.y),fmaxf(v1.z,v1.w)));
  #pragma unroll
  for (int off=1; off<64; off<<=1) m = fmaxf(m, __shfl_xor(m,off));
  if (lane==0) sR[w] = m;
  __syncthreads();
  m = fmaxf(fmaxf(sR[0],sR[1]), fmaxf(sR[2],sR[3]));
  float e0=expf(v0.x-m), e1=expf(v0.y-m), e2=expf(v0.z-m), e3=expf(v0.w-m);
  float e4=expf(v1.x-m), e5=expf(v1.y-m), e6=expf(v1.z-m), e7=expf(v1.w-m);
  float s = e0+e1+e2+e3+e4+e5+e6+e7;
  #pragma unroll
  for (int off=1; off<64; off<<=1) s += __shfl_xor(s,off);
  if (lane==0) sR[4+w] = s;
  __syncthreads();
  float inv = 1.f/(sR[4]+sR[5]+sR[6]+sR[7]);

  const float* P = ws + OFF_P + (size_t)b*512;
  const float ag0=P[448], ag1=P[449], ag2=P[450], wg=P[451];
  const float4* mr4 = (const float4*)(ws + OFF_MRW   + (size_t)b*MM);
  const float4* al4 = (const float4*)(ws + OFF_ALLOC + (size_t)b*MM);
  float4* ww4 = (float4*)(ws + OFF_WW + (size_t)b*MM);
  float4 mra = mr4[tid*2], mrb = mr4[tid*2+1];
  float4 ala = al4[tid*2], alb = al4[tid*2+1];
  float4 oa, ob;
  oa.x = wg*(ag0*mra.x + ag1*ala.x + ag2*e0*inv);
  oa.y = wg*(ag0*mra.y + ag1*ala.y + ag2*e1*inv);
  oa.z = wg*(ag0*mra.z + ag1*ala.z + ag2*e2*inv);
  oa.w = wg*(ag0*mra.w + ag1*ala.w + ag2*e3*inv);
  ob.x = wg*(ag0*mrb.x + ag1*alb.x + ag2*e4*inv);
  ob.y = wg*(ag0*mrb.y + ag1*alb.y + ag2*e5*inv);
  ob.z = wg*(ag0*mrb.z + ag1*alb.z + ag2*e6*inv);
  ob.w = wg*(ag0*mrb.w + ag1*alb.w + ag2*e7*inv);
  ww4[tid*2] = oa; ww4[tid*2+1] = ob;
  } // rep
}

// ========== K4: erase/write + read scores + online-softmax partials =======
__global__ __launch_bounds__(256) void k4_passB(
    const float* __restrict__ memory, float* __restrict__ ws)
{
  const int slice = blockIdx.x, b = blockIdx.y;
  const int tid = threadIdx.x, l16 = tid & 15, rowg = tid >> 4;
  const int lane = tid & 63, wid = tid >> 6;       // 4 waves = 4 heads
  __shared__ __align__(16) float chunk[64*68];
  __shared__ __align__(16) float sE[4*68];
  __shared__ float sHm[4], sHs[4], sHsc[4];

  const float* P = ws + OFF_P + (size_t)b*512;
  const float4 er4 = ((const float4*)(P+320))[l16];
  const float4 wv4 = ((const float4*)(P+384))[l16];
  const float4 k0 = ((const float4*)P)[     l16];
  const float4 k1 = ((const float4*)P)[16 + l16];
  const float4 k2 = ((const float4*)P)[32 + l16];
  const float4 k3 = ((const float4*)P)[48 + l16];
  const float* wwp = ws + OFF_WW + (size_t)b*MM + slice*256;
  const float4* mem4 = (const float4*)(memory + (size_t)b*MM*CC) + (size_t)slice*256*16;

  #pragma unroll 1
  for (int rep = 0; rep < REP_K4; ++rep) {
  __syncthreads();
  if (tid < 4){ sHm[tid] = -INFINITY; sHs[tid] = 0.f; }
  __syncthreads();
  const int q = lane & 15, ps = lane >> 4;
  float4 acc; acc.x=acc.y=acc.z=acc.w=0.f;

  for (int ch = 0; ch < 4; ++ch) {
    #pragma unroll
    for (int pp = 0; pp < 4; ++pp) {
      int p = pp*16 + rowg;
      int m = ch*64 + p;
      float4 v = mem4[m*16 + l16];
      float wm = wwp[m];
      float4 nv;
      nv.x = v.x*(1.f - wm*er4.x) + wm*wv4.x;
      nv.y = v.y*(1.f - wm*er4.y) + wm*wv4.y;
      nv.z = v.z*(1.f - wm*er4.z) + wm*wv4.z;
      nv.w = v.w*(1.f - wm*er4.w) + wm*wv4.w;
      *(float4*)&chunk[p*68 + (l16<<2)] = nv;
      float d0 = nv.x*k0.x+nv.y*k0.y+nv.z*k0.z+nv.w*k0.w;
      float d1 = nv.x*k1.x+nv.y*k1.y+nv.z*k1.z+nv.w*k1.w;
      float d2 = nv.x*k2.x+nv.y*k2.y+nv.z*k2.z+nv.w*k2.w;
      float d3 = nv.x*k3.x+nv.y*k3.y+nv.z*k3.z+nv.w*k3.w;
      float qq = nv.x*nv.x+nv.y*nv.y+nv.z*nv.z+nv.w*nv.w;
      #pragma unroll
      for (int off=1; off<16; off<<=1){
        d0+=__shfl_xor(d0,off); d1+=__shfl_xor(d1,off);
        d2+=__shfl_xor(d2,off); d3+=__shfl_xor(d3,off);
        qq+=__shfl_xor(qq,off);
      }
      if (l16==0){
        float inv = 1.f/(sqrtf(qq)+EPSN);
        sE[      p] = d0*inv;
        sE[ 68 + p] = d1*inv;
        sE[136 + p] = d2*inv;
        sE[204 + p] = d3*inv;
      }
    }
    __syncthreads();
    {
      float v = sE[wid*68 + lane];
      float cm = v;
      #pragma unroll
      for (int off=1; off<64; off<<=1) cm = fmaxf(cm, __shfl_xor(cm,off));
      float om = sHm[wid];
      float nm = fmaxf(om, cm);
      float scl = expf(om - nm);
      float e = expf(v - nm);
      sE[wid*68 + lane] = e;
      float es = e;
      #pragma unroll
      for (int off=1; off<64; off<<=1) es += __shfl_xor(es,off);
      if (lane==0){
        sHs[wid] = sHs[wid]*scl + es;
        sHm[wid] = nm;
        sHsc[wid] = scl;
      }
    }
    __syncthreads();
    {
      float scl = sHsc[wid];
      acc.x*=scl; acc.y*=scl; acc.z*=scl; acc.w*=scl;
      #pragma unroll
      for (int pp = 0; pp < 16; ++pp) {
        int p = ps*16 + pp;
        float e = sE[wid*68 + p];
        const float4 mv = *(const float4*)&chunk[p*68 + (q<<2)];
        acc.x += e*mv.x; acc.y += e*mv.y; acc.z += e*mv.z; acc.w += e*mv.w;
      }
    }
    __syncthreads();
  }

  #pragma unroll
  for (int off=16; off<64; off<<=1) {
    acc.x += __shfl_xor(acc.x, off);
    acc.y += __shfl_xor(acc.y, off);
    acc.z += __shfl_xor(acc.z, off);
    acc.w += __shfl_xor(acc.w, off);
  }
  if (ps == 0) {
    float* pacc = ws + OFF_PART + ((((size_t)b*8 + slice)*4 + wid)<<6);
    *(float4*)&pacc[q<<2] = acc;
  }
  if (lane == 0) {
    float* pst = ws + OFF_PSTAT + (((size_t)b*8 + slice)*4 + wid)*2;
    pst[0] = sHm[wid]; pst[1] = sHs[wid];
  }
  } // rep
}

// ================= K5: combine slice partials, normalize ==================
__global__ __launch_bounds__(256) void k5_combine(
    const float* __restrict__ ws, float* __restrict__ out)
{
  const int b = blockIdx.x, tid = threadIdx.x;
  const int head = tid >> 6, c = tid & 63;
  float M = -INFINITY;
  #pragma unroll
  for (int s = 0; s < 8; ++s)
    M = fmaxf(M, ws[OFF_PSTAT + (((size_t)b*8 + s)*4 + head)*2]);
  float S = 0.f, A = 0.f;
  #pragma unroll
  for (int s = 0; s < 8; ++s) {
    const float* pst = ws + OFF_PSTAT + (((size_t)b*8 + s)*4 + head)*2;
    float w = expf(pst[0] - M);
    S += w * pst[1];
    A += w * ws[OFF_PART + ((((size_t)b*8 + s)*4 + head)<<6) + c];
  }
  out[((size_t)b<<8) + head*64 + c] = A / S;
}

extern "C" void kernel_launch(void* const* d_in, const int* in_sizes, int n_in,
                              void* d_out, int out_size, void* d_ws, size_t ws_size,
                              hipStream_t stream) {
  const float* xi      = (const float*)d_in[0];
  const float* W       = (const float*)d_in[1];
  const float* gamma   = (const float*)d_in[2];
  const float* beta    = (const float*)d_in[3];
  const float* memory  = (const float*)d_in[4];
  const float* read_w  = (const float*)d_in[5];
  const float* write_w = (const float*)d_in[6];
  const float* usage   = (const float*)d_in[7];
  float* ws  = (float*)d_ws;
  float* out = (float*)d_out;

  k1_interface<<<dim3(256), dim3(512), 0, stream>>>(xi, W, gamma, beta, read_w, write_w, usage, ws);
  k2_fused   <<<dim3(2304), dim3(256), 0, stream>>>(memory, ws);
  k3_ww      <<<dim3(256), dim3(256), 0, stream>>>(ws);
  k4_passB   <<<dim3(8,256), dim3(256), 0, stream>>>(memory, ws);
  k5_combine <<<dim3(256), dim3(256), 0, stream>>>(ws, out);
}

// Round 11
// 385.524 us; speedup vs baseline: 1.5531x; 1.5531x over previous
//
#include <hip/hip_runtime.h>
#include <math.h>

#define MM    2048
#define CC    64
#define NIF   461
#define INS   512
#define EPSN  1e-6f

typedef unsigned long long u64;

// ---- ws float offsets ----
#define OFF_P     ((size_t)0)          // 256 x 512: rkeys0-255, wkey256-319, erase320-383, wv384-447, ag0..2+wg 448-451
#define OFF_Z     ((size_t)131072)     // 256
#define OFF_MRW   ((size_t)131328)     // 256 x 2048
#define OFF_ALLOC ((size_t)655616)     // 256 x 2048
#define OFF_SC    ((size_t)1179904)    // 256 x 2048
#define OFF_A     ((size_t)1704192)    // 256 x 4 x 64
#define OFF_S     ((size_t)1769728)    // 256 x 4
#define OFF_CNT   ((size_t)1770752)    // 256 (int)

__device__ __forceinline__ float actfn(int c, float g){
  if (c < 256)  return tanhf(g);
  if (c < 260)  return fmaxf(g,0.f) + log1pf(expf(-fabsf(g)));
  if (c < 324)  return tanhf(g);
  if (c == 324) return fmaxf(g,0.f) + log1pf(expf(-fabsf(g)));
  if (c < 389)  return 1.f/(1.f+expf(-g));
  if (c < 453)  return tanhf(g);
  if (c < 457)  return 1.f/(1.f+expf(-g));
  if (c < 460)  return g;
  return 1.f/(1.f+expf(-g));
}

// ============ KA: interface + gates + u2 + scores(+Z) + sort + alloc ============
__global__ __launch_bounds__(512) void kA(
    const float* __restrict__ xi, const float* __restrict__ W,
    const float* __restrict__ gamma, const float* __restrict__ beta,
    const float* __restrict__ memory, const float* __restrict__ read_w,
    const float* __restrict__ write_w, const float* __restrict__ usage,
    float* __restrict__ ws)
{
  const int b = blockIdx.x, tid = threadIdx.x;
  const int lane = tid & 63, wid = tid >> 6;      // 8 waves
  __shared__ __align__(16) float sxi[512], sP[512], sact[464], sT[520];
  __shared__ __align__(16) u64 keys[2048];
  __shared__ float sR[32];

  // zero per-batch accumulators (KB of previous replay is complete)
  if (tid < 256) ws[OFF_A + (size_t)b*256 + tid] = 0.f;
  if (tid < 4)   ws[OFF_S + (size_t)b*4 + tid] = 0.f;
  if (tid == 4)  ((int*)(ws + OFF_CNT))[b] = 0;

  sxi[tid] = xi[(size_t)b*INS + tid];
  __syncthreads();

  // ---- interface GEMM: 8-lane groups, 64 FMA per 3-shfl reduce ----
  {
    const int g = lane >> 3, q = lane & 7;
    const float4* x4 = (const float4*)sxi;
    #pragma unroll 1
    for (int i = 0; i < 8; ++i) {
      int c = i*64 + wid*8 + g;
      float acc = 0.f;
      if (c < NIF) {
        const float4* Wr = (const float4*)(W + (size_t)c*INS);
        #pragma unroll
        for (int t = 0; t < 16; ++t) {
          float4 wv = Wr[t*8+q];
          float4 xv = x4[t*8+q];
          acc += wv.x*xv.x + wv.y*xv.y + wv.z*xv.z + wv.w*xv.w;
        }
      }
      acc += __shfl_xor(acc,1); acc += __shfl_xor(acc,2); acc += __shfl_xor(acc,4);
      if (q == 0 && c < NIF) sT[c] = acc;
    }
  }
  __syncthreads();

  // ---- GroupNorm + activations ----
  {
    float v = (tid < NIF) ? sT[tid] : 0.f;
    float s = v, q = v*v;
    #pragma unroll
    for (int off=1; off<64; off<<=1){ s += __shfl_xor(s,off); q += __shfl_xor(q,off); }
    if (lane==0){ sR[wid]=s; sR[8+wid]=q; }
    __syncthreads();
    if (tid==0){
      float ts=0.f, tq=0.f;
      for (int i=0;i<8;i++){ ts+=sR[i]; tq+=sR[8+i]; }
      float mean = ts/(float)NIF;
      float var  = tq/(float)NIF - mean*mean;
      sR[16]=mean; sR[17]=rsqrtf(var+1e-5f);
    }
    __syncthreads();
    float mean=sR[16], rstd=sR[17];
    if (tid < NIF) sact[tid] = actfn(tid, (v-mean)*rstd*gamma[tid]+beta[tid]);
  }
  __syncthreads();

  // ---- fold keys, gates -> sP (LDS) + P (global) ----
  float* P = ws + OFF_P + (size_t)b*512;
  if (wid < 4) {
    float t = sact[wid*64 + lane];
    float q = t*t;
    #pragma unroll
    for (int off=1; off<64; off<<=1) q += __shfl_xor(q,off);
    float fk = t * (sact[256+wid] / (sqrtf(q) + EPSN));
    sP[wid*64+lane] = fk; P[wid*64+lane] = fk;
  } else if (wid == 4) {
    float t = sact[260+lane];
    float q = t*t;
    #pragma unroll
    for (int off=1; off<64; off<<=1) q += __shfl_xor(q,off);
    float fw = t * (sact[324] / (sqrtf(q) + EPSN));
    sP[256+lane] = fw; P[256+lane] = fw;
  } else if (wid == 5) {
    sP[320+lane] = sact[325+lane]; P[320+lane] = sact[325+lane];
    sP[384+lane] = sact[389+lane]; P[384+lane] = sact[389+lane];
  } else if (wid == 6 && lane == 0) {
    float a0=sact[457], a1=sact[458], a2=sact[459];
    float mx = fmaxf(a0, fmaxf(a1,a2));
    float e0=expf(a0-mx), e1=expf(a1-mx), e2=expf(a2-mx);
    float is = 1.f/(e0+e1+e2);
    P[448]=e0*is; P[449]=e1*is; P[450]=e2*is; P[451]=sact[460];
  }

  // ---- u2 + mrw + sort keys (512 thr x 1 float4) ----
  {
    const float4* us4 = (const float4*)(usage   + (size_t)b*MM);
    const float4* wr4 = (const float4*)(write_w + (size_t)b*MM);
    const float4* rw4 = (const float4*)(read_w  + (size_t)b*4*MM);
    const float fg0=sact[453], fg1=sact[454], fg2=sact[455], fg3=sact[456];
    float4 u = us4[tid], w = wr4[tid];
    float4 r0 = rw4[tid], r1 = rw4[512+tid], r2 = rw4[1024+tid], r3 = rw4[1536+tid];
    float4 mr;
    mr.x = 0.25f*(r0.x+r1.x+r2.x+r3.x);
    mr.y = 0.25f*(r0.y+r1.y+r2.y+r3.y);
    mr.z = 0.25f*(r0.z+r1.z+r2.z+r3.z);
    mr.w = 0.25f*(r0.w+r1.w+r2.w+r3.w);
    ((float4*)(ws + OFF_MRW + (size_t)b*MM))[tid] = mr;
    const int base = tid*4;
    #define U2C(comp, off)                                                     \
    { float uu  = u.comp + (1.f-u.comp)*w.comp;                                \
      float psi = (1.f-fg0*r0.comp)*(1.f-fg1*r1.comp)*(1.f-fg2*r2.comp)*(1.f-fg3*r3.comp); \
      float u2v = 1e-6f + (1.f-1e-6f)*(uu*psi);                                \
      keys[base+off] = ((u64)__float_as_uint(u2v)<<32) | (unsigned)(base+off); }
    U2C(x,0) U2C(y,1) U2C(z,2) U2C(w,3)
    #undef U2C
  }
  __syncthreads();

  // ---- score pass over all 8 slices (the HBM pass) + Z ----
  {
    const int l16 = tid & 15, rowg = tid >> 4;      // 32 rows/iter
    const float4 wk4 = ((const float4*)(sP+256))[l16];
    const float4* mem4 = (const float4*)(memory + (size_t)b*MM*CC);
    float* sc = ws + OFF_SC + (size_t)b*MM;
    float zpart = 0.f;
    #pragma unroll 8
    for (int it = 0; it < 64; ++it) {
      int m = it*32 + rowg;
      float4 v = mem4[m*16 + l16];
      float d = v.x*wk4.x + v.y*wk4.y + v.z*wk4.z + v.w*wk4.w;
      float q = v.x*v.x + v.y*v.y + v.z*v.z + v.w*v.w;
      #pragma unroll
      for (int off=1; off<16; off<<=1){ d += __shfl_xor(d,off); q += __shfl_xor(q,off); }
      if (l16==0){
        float s = d / (sqrtf(q)+EPSN);
        sc[m] = s;
        zpart += expf(s);
      }
    }
    #pragma unroll
    for (int off=1; off<64; off<<=1) zpart += __shfl_xor(zpart,off);
    if (lane==0) sR[wid] = zpart;
    __syncthreads();
    if (tid==0){
      float z=0.f;
      for (int i=0;i<8;i++) z += sR[i];
      ws[OFF_Z + b] = z;
    }
  }
  __syncthreads();

  // ---- bitonic sort (512 thr) ----
  for (int k2 = 2; k2 <= MM; k2 <<= 1) {
    for (int j = k2 >> 1; j > 0; j >>= 1) {
      #pragma unroll 2
      for (int c = tid; c < MM/2; c += 512) {
        int i   = ((c & ~(j-1)) << 1) | (c & (j-1));
        int ixj = i | j;
        u64 a = keys[i], d = keys[ixj];
        bool up = ((i & k2) == 0);
        if ((a > d) == up) { keys[i] = d; keys[ixj] = a; }
      }
      __syncthreads();
    }
  }

  // ---- cumprod scan + alloc scatter (4 elems/thread) ----
  {
    float p4[4];
    float run = 1.f;
    #pragma unroll
    for (int e=0;e<4;++e){
      float su = __uint_as_float((unsigned)(keys[tid*4+e]>>32));
      run *= su; p4[e] = run;
    }
    sT[tid] = run;
    __syncthreads();
    float incl = sT[tid];
    #pragma unroll
    for (int off=1; off<64; off<<=1) {
      float n = __shfl_up(incl, off);
      if (lane >= off) incl *= n;
    }
    float excl = __shfl_up(incl, 1);
    if (lane == 0) excl = 1.f;
    if (lane == 63) sR[16+wid] = incl;
    __syncthreads();
    float base = 1.f;
    for (int w2 = 0; w2 < wid; ++w2) base *= sR[16+w2];
    float E = base * excl;
    float* allocp = ws + OFF_ALLOC + (size_t)b*MM;
    #pragma unroll
    for (int e=0;e<4;++e){
      u64 kk = keys[tid*4+e];
      float su = __uint_as_float((unsigned)(kk>>32));
      unsigned idx = (unsigned)(kk & 0xFFFFFFFFu);
      float cp = E * (e ? p4[e-1] : 1.f);
      allocp[idx] = (1.f - su) * cp;
    }
  }
}

// ============ KB: ww + erase/write + read scores + PV + finalize ============
__global__ __launch_bounds__(256) void kB(
    const float* __restrict__ memory, float* __restrict__ ws,
    float* __restrict__ out)
{
  const int slice = blockIdx.x, b = blockIdx.y;
  const int tid = threadIdx.x, l16 = tid & 15, rowg = tid >> 4;
  const int lane = tid & 63, wid = tid >> 6;       // 4 waves = 4 heads
  __shared__ __align__(16) float chunk[64*68];
  __shared__ __align__(16) float sE[4*68];
  __shared__ float wwL[256];
  __shared__ int sFlag;

  const float* P = ws + OFF_P + (size_t)b*512;
  const float4 er4 = ((const float4*)(P+320))[l16];
  const float4 wv4 = ((const float4*)(P+384))[l16];
  const float4 k0 = ((const float4*)P)[     l16];
  const float4 k1 = ((const float4*)P)[16 + l16];
  const float4 k2 = ((const float4*)P)[32 + l16];
  const float4 k3 = ((const float4*)P)[48 + l16];
  const float4* mem4 = (const float4*)(memory + (size_t)b*MM*CC) + (size_t)slice*256*16;

  // ww for this slice
  {
    const float ag0=P[448], ag1=P[449], ag2=P[450], wg=P[451];
    const float invZ = 1.f / ws[OFF_Z + b];
    int mg = slice*256 + tid;
    float wcw = expf(ws[OFF_SC + (size_t)b*MM + mg]) * invZ;
    float al  = ws[OFF_ALLOC + (size_t)b*MM + mg];
    float mr  = ws[OFF_MRW   + (size_t)b*MM + mg];
    wwL[tid] = wg*(ag0*mr + ag1*al + ag2*wcw);
  }
  __syncthreads();

  const int q = lane & 15, ps = lane >> 4;
  float4 acc; acc.x=acc.y=acc.z=acc.w=0.f;
  float S_acc = 0.f;

  for (int ch = 0; ch < 4; ++ch) {
    #pragma unroll
    for (int pp = 0; pp < 4; ++pp) {
      int p = pp*16 + rowg;
      int m = ch*64 + p;
      float4 v = mem4[m*16 + l16];
      float wm = wwL[m];
      float4 nv;
      nv.x = v.x*(1.f - wm*er4.x) + wm*wv4.x;
      nv.y = v.y*(1.f - wm*er4.y) + wm*wv4.y;
      nv.z = v.z*(1.f - wm*er4.z) + wm*wv4.z;
      nv.w = v.w*(1.f - wm*er4.w) + wm*wv4.w;
      *(float4*)&chunk[p*68 + (l16<<2)] = nv;
      float d0 = nv.x*k0.x+nv.y*k0.y+nv.z*k0.z+nv.w*k0.w;
      float d1 = nv.x*k1.x+nv.y*k1.y+nv.z*k1.z+nv.w*k1.w;
      float d2 = nv.x*k2.x+nv.y*k2.y+nv.z*k2.z+nv.w*k2.w;
      float d3 = nv.x*k3.x+nv.y*k3.y+nv.z*k3.z+nv.w*k3.w;
      float qq = nv.x*nv.x+nv.y*nv.y+nv.z*nv.z+nv.w*nv.w;
      #pragma unroll
      for (int off=1; off<16; off<<=1){
        d0+=__shfl_xor(d0,off); d1+=__shfl_xor(d1,off);
        d2+=__shfl_xor(d2,off); d3+=__shfl_xor(d3,off);
        qq+=__shfl_xor(qq,off);
      }
      if (l16==0){
        float inv = 1.f/(sqrtf(qq)+EPSN);
        sE[      p] = d0*inv;
        sE[ 68 + p] = d1*inv;
        sE[136 + p] = d2*inv;
        sE[204 + p] = d3*inv;
      }
    }
    __syncthreads();
    // exp (no max) + per-head chunk sum
    {
      float e = expf(sE[wid*68 + lane]);
      sE[wid*68 + lane] = e;
      float es = e;
      #pragma unroll
      for (int off=1; off<64; off<<=1) es += __shfl_xor(es,off);
      S_acc += es;
    }
    __syncthreads();
    // PV accumulate
    {
      #pragma unroll
      for (int pp = 0; pp < 16; ++pp) {
        int p = ps*16 + pp;
        float e = sE[wid*68 + p];
        const float4 mv = *(const float4*)&chunk[p*68 + (q<<2)];
        acc.x += e*mv.x; acc.y += e*mv.y; acc.z += e*mv.z; acc.w += e*mv.w;
      }
    }
    __syncthreads();
  }

  // reduce p-range partials, atomic into per-batch A, S
  #pragma unroll
  for (int off=16; off<64; off<<=1) {
    acc.x += __shfl_xor(acc.x, off);
    acc.y += __shfl_xor(acc.y, off);
    acc.z += __shfl_xor(acc.z, off);
    acc.w += __shfl_xor(acc.w, off);
  }
  if (ps == 0) {
    float* A = ws + OFF_A + (size_t)b*256 + (wid<<6) + (q<<2);
    atomicAdd(&A[0], acc.x); atomicAdd(&A[1], acc.y);
    atomicAdd(&A[2], acc.z); atomicAdd(&A[3], acc.w);
  }
  if (lane == 0) atomicAdd(&ws[OFF_S + (size_t)b*4 + wid], S_acc);

  // last-block finalize
  __threadfence();
  __syncthreads();
  if (tid == 0) {
    int old = atomicAdd(&((int*)(ws + OFF_CNT))[b], 1);
    sFlag = (old == 7);
  }
  __syncthreads();
  if (sFlag) {
    int h = tid >> 6, c = tid & 63;
    float Sv = atomicAdd(&ws[OFF_S + (size_t)b*4 + h], 0.f);
    float Av = atomicAdd(&ws[OFF_A + (size_t)b*256 + h*64 + c], 0.f);
    out[((size_t)b<<8) + tid] = Av / Sv;
  }
}

extern "C" void kernel_launch(void* const* d_in, const int* in_sizes, int n_in,
                              void* d_out, int out_size, void* d_ws, size_t ws_size,
                              hipStream_t stream) {
  const float* xi      = (const float*)d_in[0];
  const float* W       = (const float*)d_in[1];
  const float* gamma   = (const float*)d_in[2];
  const float* beta    = (const float*)d_in[3];
  const float* memory  = (const float*)d_in[4];
  const float* read_w  = (const float*)d_in[5];
  const float* write_w = (const float*)d_in[6];
  const float* usage   = (const float*)d_in[7];
  float* ws  = (float*)d_ws;
  float* out = (float*)d_out;

  kA<<<dim3(256), dim3(512), 0, stream>>>(xi, W, gamma, beta, memory, read_w, write_w, usage, ws);
  kB<<<dim3(8,256), dim3(256), 0, stream>>>(memory, ws, out);
}